// Round 5
// baseline (165.982 us; speedup 1.0000x reference)
//
#include <hip/hip_runtime.h>
#include <hip/hip_bf16.h>

constexpr int NB = 8;      // batch
constexpr int T  = 2048;   // seq
constexpr int C  = 1024;   // embed
constexpr int Hd = 128;    // head size

typedef short bf16x8 __attribute__((ext_vector_type(8)));
typedef float floatx4 __attribute__((ext_vector_type(4)));

__device__ __forceinline__ ushort f2bf(float x) {
    return __builtin_bit_cast(ushort, __float2bfloat16(x));
}
__device__ __forceinline__ float bf2f(ushort u) {
    unsigned int x = ((unsigned int)u) << 16;
    return __builtin_bit_cast(float, x);
}
__device__ __forceinline__ void async16(ushort* lds, const ushort* g) {
    __builtin_amdgcn_global_load_lds(
        (const __attribute__((address_space(1))) unsigned int*)g,
        (__attribute__((address_space(3))) unsigned int*)lds, 16, 0, 0);
}

// ---------------------------------------------------------------------------
// Kernel 1: fused fp32->bf16 convert for X and stacked W (Wq scaled). UNCHANGED.
// ---------------------------------------------------------------------------
__global__ __launch_bounds__(256) void convert_xw(
    const float* __restrict__ X, const float* __restrict__ Wq,
    const float* __restrict__ Wk, const float* __restrict__ Wv,
    ushort* __restrict__ Xb, ushort* __restrict__ Wb)
{
    int bid = blockIdx.x;
    if (bid < 8192) {
        size_t i = ((size_t)bid * 256 + threadIdx.x) * 8;
        float4 a = *(const float4*)&X[i];
        float4 b = *(const float4*)&X[i + 4];
        bf16x8 o;
        o[0] = (short)f2bf(a.x); o[1] = (short)f2bf(a.y);
        o[2] = (short)f2bf(a.z); o[3] = (short)f2bf(a.w);
        o[4] = (short)f2bf(b.x); o[5] = (short)f2bf(b.y);
        o[6] = (short)f2bf(b.z); o[7] = (short)f2bf(b.w);
        *(bf16x8*)&Xb[i] = o;
    } else {
        int g = (bid - 8192) * 256 + threadIdx.x;
        size_t base = (size_t)g * 8;
        int sel = (int)(base >> 17);
        const float* W = sel == 0 ? Wq : (sel == 1 ? Wk : Wv);
        float s = (sel == 0) ? 0.12751744f : 1.0f;     // log2e/sqrt(128) in Wq
        size_t off = base - (size_t)sel * 131072;
        float4 a = *(const float4*)&W[off];
        float4 b = *(const float4*)&W[off + 4];
        bf16x8 o;
        o[0] = (short)f2bf(a.x * s); o[1] = (short)f2bf(a.y * s);
        o[2] = (short)f2bf(a.z * s); o[3] = (short)f2bf(a.w * s);
        o[4] = (short)f2bf(b.x * s); o[5] = (short)f2bf(b.y * s);
        o[6] = (short)f2bf(b.z * s); o[7] = (short)f2bf(b.w * s);
        *(bf16x8*)&Wb[base] = o;
    }
}

// ---------------------------------------------------------------------------
// Kernel 2: QKV GEMM bf16, BM=128 BN=64 BK=128. UNCHANGED from R4.
// ---------------------------------------------------------------------------
__global__ __launch_bounds__(256) void qkv_gemm(
    const ushort* __restrict__ Xb, const ushort* __restrict__ Wb,
    ushort* __restrict__ Qo, ushort* __restrict__ Ko, ushort* __restrict__ Vt)
{
    __shared__ ushort SM[24576];          // 48KB: Al(16384) + Bl(8192); TL overlays
    ushort* Al = SM;                      // 128x128
    ushort* Bl = SM + 16384;              // 64x128
    const int m0 = blockIdx.x * 128;
    const int n0 = blockIdx.y * 64;       // row into stacked Wb [384][1024]
    const int tid = threadIdx.x, lane = tid & 63, wave = tid >> 6;
    const int quad = lane >> 4, colL = lane & 15;
    const int wm = (wave & 1) * 64, wn = (wave >> 1) * 32;
    const int lr4 = lane >> 4;            // row within 4-row staging chunk
    const int cg  = lane & 15;            // LDS 16B column group

    floatx4 acc[4][2] = {};

    for (int k0 = 0; k0 < C; k0 += 128) {
        for (int t = 0; t < 8; ++t) {
            int q = wave * 8 + t;
            int row = q * 4 + lr4;
            async16(&Al[q * 512 + lane * 8],
                    &Xb[(size_t)(m0 + row) * C + k0 + ((cg ^ (row & 7)) * 8)]);
        }
        for (int t = 0; t < 4; ++t) {
            int q = wave * 4 + t;
            int row = q * 4 + lr4;
            async16(&Bl[q * 512 + lane * 8],
                    &Wb[(size_t)(n0 + row) * C + k0 + ((cg ^ (row & 7)) * 8)]);
        }
        __syncthreads();

        for (int kk = 0; kk < 4; ++kk) {
            bf16x8 af[4], bfr[2];
            for (int mt = 0; mt < 4; ++mt)
                af[mt] = *(const bf16x8*)
                    &Al[(wm + mt * 16 + colL) * 128 + (((kk * 4 + quad) ^ (colL & 7))) * 8];
            for (int nt = 0; nt < 2; ++nt)
                bfr[nt] = *(const bf16x8*)
                    &Bl[(wn + nt * 16 + colL) * 128 + (((kk * 4 + quad) ^ (colL & 7))) * 8];
            for (int mt = 0; mt < 4; ++mt)
                for (int nt = 0; nt < 2; ++nt)
                    acc[mt][nt] = __builtin_amdgcn_mfma_f32_16x16x32_bf16(
                        af[mt], bfr[nt], acc[mt][nt], 0, 0, 0);
        }
        __syncthreads();
    }

    const int sel = n0 >> 7;              // 0,0,1,1,2,2
    const int h0 = n0 & 127;              // 0 or 64
    if (sel < 2) {
        ushort* dst = sel == 0 ? Qo : Ko;
        for (int mt = 0; mt < 4; ++mt)
            for (int nt = 0; nt < 2; ++nt)
                for (int r = 0; r < 4; ++r) {
                    int row = m0 + wm + mt * 16 + quad * 4 + r;
                    int h = h0 + wn + nt * 16 + colL;
                    dst[(size_t)row * Hd + h] = f2bf(acc[mt][nt][r]);
                }
    } else {
        // V: transpose 128t x 64h tile through LDS scratch TL[128][66]
        ushort* TL = SM;                  // 8448 ushorts, overlays Al/Bl
        for (int mt = 0; mt < 4; ++mt)
            for (int nt = 0; nt < 2; ++nt)
                for (int r = 0; r < 4; ++r)
                    TL[(wm + mt * 16 + quad * 4 + r) * 66 + wn + nt * 16 + colL] =
                        f2bf(acc[mt][nt][r]);
        __syncthreads();
        const int b = m0 >> 11, tb = m0 & 2047;
        const int h = tid & 63, tq = tid >> 6;     // thread: h col, 32-t strip
        for (int st = 0; st < 4; ++st) {
            int t0 = tq * 32 + st * 8;
            bf16x8 o;
            for (int jx = 0; jx < 8; ++jx)
                o[jx] = (short)TL[(t0 + jx) * 66 + h];
            *(bf16x8*)&Vt[((size_t)b * Hd + h0 + h) * T + tb + t0] = o;
        }
    }
}

// ---------------------------------------------------------------------------
// Kernel 3 (R5): TRUE FLASH attention — no partials, no combine kernel.
// Block = (b, qt) 64-row q-tile; grid 8*32 = 256 = 1 block/CU, all resident.
// Loop over key chunks c = 0..cmax (cmax = (64qt+63)/128; 1..16 chunks).
// 4 waves x 16 q-rows: peak live regs ~110 (accS 32 + Oacc 32 + qa 16 + sm 12
// + addr) at cap 256 (__launch_bounds__(256,2)) — BELOW R0's proven ~130.
// R2's version of this idea died only because 512-thread bounds capped VGPR
// at 128. Per-chunk sequence is R0's proven one: accS retires into LDS-P
// (overlaying K region, per-wave private) BEFORE pa/Oacc phase.
// Online softmax: sc = exp2(m_old - m_new); at c==0 m_old=-inf -> sc=0,
// branch-free. Output written fp32 directly.
// ---------------------------------------------------------------------------
__global__ __launch_bounds__(256, 2) void attn_flash(
    const ushort* __restrict__ Q, const ushort* __restrict__ Kg,
    const ushort* __restrict__ Vt, float* __restrict__ out)
{
    __shared__ ushort Kl[128 * 128];   // 32KB K chunk [key][h] swz; P overlays
    __shared__ ushort Vl[128 * 128];   // 32KB V chunk [h][key] swz

    const int tid = threadIdx.x, lane = tid & 63, wave = tid >> 6;
    const int quad = lane >> 4, colL = lane & 15;

    const int id = blockIdx.x;         // 256 blocks; heavy (qt=31) first
    const int b = id & 7;
    const int qt = 31 - (id >> 3);
    const int q0 = qt * 64;
    const int cmax = (q0 + 63) >> 7;

    // Q fragments: wave owns rows [q0 + wave*16, +16)
    bf16x8 qa[4];
    {
        const ushort* qp =
            &Q[((size_t)b * T + q0 + wave * 16 + colL) * Hd + quad * 8];
        for (int ks = 0; ks < 4; ++ks)
            qa[ks] = *(const bf16x8*)&qp[ks * 32];
    }

    floatx4 Oacc[8] = {};
    float m_r[4], l_r[4];
    for (int rr = 0; rr < 4; ++rr) { m_r[rr] = -__builtin_inff(); l_r[rr] = 0.f; }

    const int r16 = tid >> 4, p16 = tid & 15;

    for (int c = 0; c <= cmax; ++c) {
        if (c > 0) __syncthreads();    // [A] prev chunk's P/V reads complete
        const int k0 = c * 128;
        for (int t = 0; t < 8; ++t) {
            int row = t * 16 + r16;
            async16(&Kl[t * 2048 + tid * 8],
                    &Kg[((size_t)b * T + k0 + row) * Hd + ((p16 ^ (row & 15)) * 8)]);
        }
        for (int t = 0; t < 8; ++t) {
            int hrow = t * 16 + r16;
            async16(&Vl[t * 2048 + tid * 8],
                    &Vt[((size_t)b * Hd + hrow) * T + k0 + ((p16 ^ (hrow & 15)) * 8)]);
        }
        __syncthreads();               // [B] K,V visible (drains vmcnt)

        floatx4 accS[8] = {};
        for (int ks = 0; ks < 4; ++ks)
            for (int nt = 0; nt < 8; ++nt) {
                int krow = nt * 16 + colL;
                bf16x8 kb = *(const bf16x8*)&Kl[krow * 128 + (((ks * 4 + quad) ^ colL) * 8)];
                accS[nt] = __builtin_amdgcn_mfma_f32_16x16x32_bf16(qa[ks], kb, accS[nt], 0, 0, 0);
            }

        if (c == cmax) {               // causal mask (only last chunk can hit diag)
            for (int nt = 0; nt < 8; ++nt)
                for (int rr = 0; rr < 4; ++rr) {
                    int lrow = q0 + wave * 16 + quad * 4 + rr;
                    int lcol = k0 + nt * 16 + colL;
                    if (lcol > lrow) accS[nt][rr] = -__builtin_inff();
                }
        }
        __syncthreads();               // [C] K reads done -> P may overlay Kl

        // online softmax: chunk max, merge, rescale
        float sc[4];
        for (int rr = 0; rr < 4; ++rr) {
            float mx = accS[0][rr];
            for (int nt = 1; nt < 8; ++nt) mx = fmaxf(mx, accS[nt][rr]);
            for (int off = 1; off < 16; off <<= 1)
                mx = fmaxf(mx, __shfl_xor(mx, off, 64));
            float nm = fmaxf(m_r[rr], mx);     // finite (diag key always live)
            sc[rr] = __builtin_amdgcn_exp2f(m_r[rr] - nm);   // c==0: exp2(-inf)=0
            m_r[rr] = nm;
        }
        for (int th = 0; th < 8; ++th)
            for (int rr = 0; rr < 4; ++rr)
                Oacc[th][rr] *= sc[rr];

        // exp -> P (per-wave 16x128 region overlaying Kl), l update
        ushort* Pw = &Kl[wave * 2048];         // [16 rows][128], col^((row&7)<<4)
        {
            float ls[4] = {0.f, 0.f, 0.f, 0.f};
            for (int nt = 0; nt < 8; ++nt)
                for (int rr = 0; rr < 4; ++rr) {
                    float p = __builtin_amdgcn_exp2f(accS[nt][rr] - m_r[rr]);
                    ls[rr] += p;
                    int prow = quad * 4 + rr;
                    Pw[prow * 128 + ((nt * 16 + colL) ^ ((prow & 7) << 4))] = f2bf(p);
                }
            for (int rr = 0; rr < 4; ++rr) {
                float s = ls[rr];
                for (int off = 1; off < 16; off <<= 1)
                    s += __shfl_xor(s, off, 64);
                l_r[rr] = l_r[rr] * sc[rr] + s;
            }
        }

        // pa read (same-wave RAW through LDS; lgkmcnt handled by compiler)
        bf16x8 pa[4];
        {
            const int prow = colL;
            const int sw = (prow & 7) << 4;
            for (int ks = 0; ks < 4; ++ks)
                pa[ks] = *(const bf16x8*)&Pw[prow * 128 + ((ks * 32 + quad * 8) ^ sw)];
        }

        for (int ks = 0; ks < 4; ++ks)
            for (int th = 0; th < 8; ++th) {
                int hrow = th * 16 + colL;
                bf16x8 vb = *(const bf16x8*)&Vl[hrow * 128 + (((ks * 4 + quad) ^ colL) * 8)];
                Oacc[th] = __builtin_amdgcn_mfma_f32_16x16x32_bf16(pa[ks], vb, Oacc[th], 0, 0, 0);
            }
    }

    // epilogue: normalize + fp32 out
    float inv[4];
    for (int rr = 0; rr < 4; ++rr) inv[rr] = 1.0f / l_r[rr];
    for (int th = 0; th < 8; ++th)
        for (int rr = 0; rr < 4; ++rr) {
            int row = q0 + wave * 16 + quad * 4 + rr;
            out[((size_t)b * T + row) * Hd + th * 16 + colL] = Oacc[th][rr] * inv[rr];
        }
}

// ---------------------------------------------------------------------------
extern "C" void kernel_launch(void* const* d_in, const int* in_sizes, int n_in,
                              void* d_out, int out_size, void* d_ws, size_t ws_size,
                              hipStream_t stream) {
    const float* x  = (const float*)d_in[0];
    const float* Wq = (const float*)d_in[1];
    const float* Wk = (const float*)d_in[2];
    const float* Wv = (const float*)d_in[3];
    float* out = (float*)d_out;

    // ws: Xb 33.55 MB + Wb 0.79 MB + Q/K/Vt 3*4.19 MB  (~47 MB; no partials)
    char* w = (char*)d_ws;
    ushort* Xb = (ushort*)w;  w += (size_t)33554432;
    ushort* Wb = (ushort*)w;  w += (size_t)786432;
    ushort* Qb  = (ushort*)w;  w += (size_t)NB * T * Hd * 2;
    ushort* Kb  = (ushort*)w;  w += (size_t)NB * T * Hd * 2;
    ushort* Vtb = (ushort*)w;  w += (size_t)NB * T * Hd * 2;

    convert_xw<<<8384, 256, 0, stream>>>(x, Wq, Wk, Wv, Xb, Wb);
    qkv_gemm<<<dim3(128, 6), 256, 0, stream>>>(Xb, Wb, Qb, Kb, Vtb);
    attn_flash<<<256, 256, 0, stream>>>(Qb, Kb, Vtb, out);
}